// Round 12
// baseline (84.748 us; speedup 1.0000x reference)
//
#include <hip/hip_runtime.h>
#include <hip/hip_bf16.h>

// TwinPolicy, pure-bf16 MFMA pipeline (5 launches):
//   prep_small: fold Wab=(We1@W2) -> wabh (packed), bab          (66 blocks)
//   gemm1: h1p = pack(relu(x @ W1.T + b1)); A and W converted f32->bf16
//          IN-FLIGHT (reg-staged, ds_write) -- no pack round-trip via HBM.
//   gemm2: ABbf = bf16(h1 @ Wab.T + bab)     64x64, 512 blocks
//   edge_fill (block-specialized): blocks 0..511 zero-fill 67MB output;
//     blocks 512..2559 compute v[e]=exp(s[e]) + block partial Z (no max-sub:
//     |s| = O(1) for these weight scales).
//   scatter_probs: redundant Z-reduce per block + out[src,dst] = v/Z

typedef unsigned short u16;
typedef unsigned int   u32;
typedef __attribute__((ext_vector_type(8))) short bf16x8;
typedef __attribute__((ext_vector_type(4))) float f32x4;

#define N_NODES 4096
#define E_EDGES 131072
#define AS1 __attribute__((address_space(1)))
#define AS3 __attribute__((address_space(3)))

__device__ __forceinline__ u16 f2bf(float f) {
    u32 u = __float_as_uint(f);
    return (u16)((u + 0x7FFFu + ((u >> 16) & 1u)) >> 16);
}
__device__ __forceinline__ float bflo(u32 w) { return __uint_as_float(w << 16); }
__device__ __forceinline__ float bfhi(u32 w) { return __uint_as_float(w & 0xffff0000u); }

// ---------------------------------------------------------------------------
// prep_small (66 blocks):
//   [0,64):  Wab[r][c] = (r<256 ? We1a@W2 : We1b@W2), packed bf16 W-layout
//   [64,66): bab[r] = (r<256 ? be1[r] : 0) + dot(We1 row-part, b2)
// ---------------------------------------------------------------------------
__global__ __launch_bounds__(256)
void prep_small(const float* __restrict__ We1, const float* __restrict__ W2,
                const float* __restrict__ b2, const float* __restrict__ be1,
                u16* __restrict__ wabh, float* __restrict__ bab)
{
    const int bid = blockIdx.x;
    if (bid < 64) {
        const int r0 = bid * 8;
        const int c  = threadIdx.x;
        float acc[8] = {};
        for (int k = 0; k < 256; ++k) {
            const float w2 = W2[k * 256 + c];
            #pragma unroll
            for (int j = 0; j < 8; ++j) {
                const int r = r0 + j;
                acc[j] += We1[(size_t)(r & 255) * 512 + ((r >> 8) << 8) + k] * w2;
            }
        }
        const int kc = c >> 6, kb = (c >> 3) & 7, e = c & 7;
        #pragma unroll
        for (int j = 0; j < 8; ++j) {
            const int r = r0 + j;
            wabh[(((((size_t)(r >> 6) << 2) + kc) << 3) + kb) * 512 + (size_t)(r & 63) * 8 + e]
                = f2bf(acc[j]);
        }
    } else {
        const int r = (bid - 64) * 256 + threadIdx.x;
        const int i = r & 255;
        const int koff = (r >> 8) << 8;
        float acc = (r < 256) ? be1[i] : 0.0f;
        for (int k = 0; k < 256; k += 4) {
            const float4 w = *(const float4*)(We1 + (size_t)i * 512 + koff + k);
            const float4 b = *(const float4*)(b2 + k);
            acc += w.x * b.x + w.y * b.y + w.z * b.z + w.w * b.w;
        }
        bab[r] = acc;
    }
}

// ---------------------------------------------------------------------------
// GEMM1: h1p = relu(x @ W1.T + b1), f32 inputs converted to bf16 in-flight.
// BM=32, BN=64, KC=16 (BK=64), 4 waves, grid (128,4) = 512 blocks (2/CU).
// A-stage: thread (rA=tid&31, kbA=tid>>5) reads 32B f32 of row rA
//   (lane r and r+32 share one 64B line), cvt -> ds_write 16B linear (tid*16).
// W-stage: thread (cW=tid&63, kb2=tid>>6) reads 64B f32 (full line),
//   cvt -> two 16B ds_writes, contiguous 1KB per wave.
// Epilogue: packed A-layout for gemm2 (KCnext=4). Bit-identical to the
// previous prep_all+gemm1 pipeline (same f2bf rounding, same MFMA order).
// ---------------------------------------------------------------------------
__global__ __launch_bounds__(256)
void mfma_gemm1(const float* __restrict__ X, const float* __restrict__ W1,
                const float* __restrict__ bias, u16* __restrict__ Cout)
{
    __shared__ u16 As[2][2048];   // [kb(8)][r(32)][e(8)]
    __shared__ u16 Bs[2][4096];   // [kb(8)][c(64)][e(8)]
    const int tid  = threadIdx.x;
    const int wv   = tid >> 6;
    const int lane = tid & 63;
    const int bp   = blockIdx.x;          // 0..127: 32-row block
    const int bn   = blockIdx.y;          // 0..3:   64-col panel
    const int p    = bp >> 1;
    const int r0   = (bp & 1) << 5;
    const int KC   = 16;

    const int rA  = tid & 31;
    const int kbA = tid >> 5;
    const float* gxa = X + ((size_t)(p * 64 + r0 + rA)) * 1024 + kbA * 8;
    const int cW  = tid & 63;
    const int kb2 = tid >> 6;
    const float* gwp = W1 + ((size_t)(bn * 64 + cW)) * 1024 + kb2 * 16;

    float4 a0, a1, w0, w1, w2, w3;
    auto gload = [&](int t) {
        const float* pa = gxa + t * 64;
        a0 = *(const float4*)pa;
        a1 = *(const float4*)(pa + 4);
        const float* pw = gwp + t * 64;
        w0 = *(const float4*)pw;        w1 = *(const float4*)(pw + 4);
        w2 = *(const float4*)(pw + 8);  w3 = *(const float4*)(pw + 12);
    };
    auto cvt_store = [&](int b) {
        const float av[8] = {a0.x, a0.y, a0.z, a0.w, a1.x, a1.y, a1.z, a1.w};
        u32 aw[4];
        #pragma unroll
        for (int q = 0; q < 4; ++q)
            aw[q] = (u32)f2bf(av[2 * q]) | ((u32)f2bf(av[2 * q + 1]) << 16);
        uint4 avv = {aw[0], aw[1], aw[2], aw[3]};
        *(uint4*)(&As[b][tid << 3]) = avv;          // linear: (kbA*32+rA)*8 u16

        const float wvv[16] = {w0.x, w0.y, w0.z, w0.w, w1.x, w1.y, w1.z, w1.w,
                               w2.x, w2.y, w2.z, w2.w, w3.x, w3.y, w3.z, w3.w};
        u32 ww[8];
        #pragma unroll
        for (int q = 0; q < 8; ++q)
            ww[q] = (u32)f2bf(wvv[2 * q]) | ((u32)f2bf(wvv[2 * q + 1]) << 16);
        uint4 wv0 = {ww[0], ww[1], ww[2], ww[3]};
        uint4 wv1 = {ww[4], ww[5], ww[6], ww[7]};
        *(uint4*)(&Bs[b][(((kb2 << 1) + 0) * 64 + cW) << 3]) = wv0;
        *(uint4*)(&Bs[b][(((kb2 << 1) + 1) * 64 + cW) << 3]) = wv1;
    };

    f32x4 acc[2];
    #pragma unroll
    for (int m = 0; m < 2; ++m) acc[m] = (f32x4){0.f, 0.f, 0.f, 0.f};

    const int kq  = lane >> 4;
    const int r16 = lane & 15;

    auto compute = [&](int b) {
        #pragma unroll
        for (int s = 0; s < 2; ++s) {
            const int kb = (s << 2) + kq;
            const bf16x8 bf = *(const bf16x8*)&Bs[b][((kb << 6) + (wv << 4) + r16) << 3];
            #pragma unroll
            for (int m = 0; m < 2; ++m) {
                const bf16x8 af = *(const bf16x8*)&As[b][((kb << 5) + (m << 4) + r16) << 3];
                acc[m] = __builtin_amdgcn_mfma_f32_16x16x32_bf16(af, bf, acc[m], 0, 0, 0);
            }
        }
    };

    gload(0);
    cvt_store(0);
    __syncthreads();
    int buf = 0;
    for (int t = 0; t < KC; ++t) {
        if (t + 1 < KC) gload(t + 1);      // issue early: hides under MFMA
        compute(buf);
        if (t + 1 < KC) cvt_store(buf ^ 1);
        __syncthreads();
        buf ^= 1;
    }

    // C/D: col=lane&15, row=(lane>>4)*4+j.  Packed A-layout epilogue (KCnext=4).
    const int col  = (bn << 6) + (wv << 4) + r16;
    const float bv = bias[col];
    const int kb2o = (wv << 1) | (r16 >> 3);
    const int e2   = r16 & 7;
    u16* Cp = Cout + (((((size_t)p * 4 + bn) << 3) + kb2o) << 9) + e2;
    #pragma unroll
    for (int m = 0; m < 2; ++m)
        #pragma unroll
        for (int j = 0; j < 4; ++j) {
            const float v = fmaxf(acc[m][j] + bv, 0.0f);
            const int r64 = r0 + (kq << 2) + (m << 4) + j;
            Cp[(size_t)r64 << 3] = f2bf(v);
        }
}

// ---------------------------------------------------------------------------
// GEMM2: AB = h1 @ Wab.T + bab, bf16 row-major out.
// 64x64 tile, KC=4, 4 waves, grid (64,8) = 512 blocks.
// ---------------------------------------------------------------------------
__global__ __launch_bounds__(256)
void mfma_gemm2(const u16* __restrict__ A, const u16* __restrict__ W,
                const float* __restrict__ bias, u16* __restrict__ Cout)
{
    __shared__ u16 As[2][4096];
    __shared__ u16 Bs[2][4096];
    const int tid  = threadIdx.x;
    const int wv   = tid >> 6;
    const int lane = tid & 63;
    const int bp   = blockIdx.x;
    const int bn   = blockIdx.y;
    const int KC   = 4;
    const int Nout = 512;

    auto stage = [&](int b, int t) {
        const u16* ga = A + (((size_t)bp * KC + t) << 12);
        const u16* gw = W + (((size_t)bn * KC + t) << 12);
        #pragma unroll
        for (int c = 0; c < 2; ++c) {
            const int ch = (wv << 1) + c;
            __builtin_amdgcn_global_load_lds(
                (const AS1 u32*)(ga + (ch << 9) + (lane << 3)),
                (AS3 u32*)(&As[b][ch << 9]), 16, 0, 0);
            __builtin_amdgcn_global_load_lds(
                (const AS1 u32*)(gw + (ch << 9) + (lane << 3)),
                (AS3 u32*)(&Bs[b][ch << 9]), 16, 0, 0);
        }
    };

    f32x4 acc[4];
    #pragma unroll
    for (int m = 0; m < 4; ++m) acc[m] = (f32x4){0.f, 0.f, 0.f, 0.f};

    const int kq  = lane >> 4;
    const int r16 = lane & 15;

    auto compute = [&](int b) {
        #pragma unroll
        for (int s = 0; s < 2; ++s) {
            const int kb = (s << 2) + kq;
            const bf16x8 bf = *(const bf16x8*)&Bs[b][((kb << 6) + (wv << 4) + r16) << 3];
            #pragma unroll
            for (int m = 0; m < 4; ++m) {
                const bf16x8 af = *(const bf16x8*)&As[b][((kb << 6) + (m << 4) + r16) << 3];
                acc[m] = __builtin_amdgcn_mfma_f32_16x16x32_bf16(af, bf, acc[m], 0, 0, 0);
            }
        }
    };

    stage(0, 0);
    __syncthreads();
    int buf = 0;
    for (int t = 0; t < KC; ++t) {
        if (t + 1 < KC) stage(buf ^ 1, t + 1);
        compute(buf);
        __syncthreads();
        buf ^= 1;
    }

    const int col  = (bn << 6) + (wv << 4) + r16;
    const float bv = bias[col];
    #pragma unroll
    for (int m = 0; m < 4; ++m)
        #pragma unroll
        for (int j = 0; j < 4; ++j) {
            const float v = acc[m][j] + bv;
            const int row = (bp << 6) + (kq << 2) + (m << 4) + j;
            Cout[(size_t)row * Nout + col] = f2bf(v);
        }
}

// ---------------------------------------------------------------------------
// Block-specialized edge + fill (NO inter-block sync needed):
//   blocks [0,512):    zero-fill 67MB output (32 float4/thread)
//   blocks [512,2560): v[e] = exp(score[e]) (no max-sub; |s| = O(1)),
//                      block-partial Z -> part[cb] (only l5==0 lanes add).
// ---------------------------------------------------------------------------
__global__ __launch_bounds__(256)
void edge_fill(const u16* __restrict__ AB, const int* __restrict__ idx,
               const float* __restrict__ We2, const float* __restrict__ be2p,
               float* __restrict__ vbuf, float* __restrict__ part,
               float4* __restrict__ out4)
{
    const int bid = blockIdx.x;
    const int tid = threadIdx.x;

    if (bid < 512) {
        // 512 blk * 256 thr * 32 float4 * 16B = 67.1 MB
        float4* op = out4 + (size_t)bid * 8192 + tid;
        const float4 z = {0.f, 0.f, 0.f, 0.f};
        #pragma unroll 8
        for (int q = 0; q < 32; ++q)
            op[(size_t)q * 256] = z;
        return;
    }

    __shared__ float sm[256];
    const int cb   = bid - 512;                  // 0..2047
    const int lane = tid & 63;
    const int sub  = lane >> 5;
    const int l5   = lane & 31;
    const int wid  = (cb * 256 + tid) >> 6;      // 0..8191
    const float be2 = be2p[0];

    float w2v[8];
    #pragma unroll
    for (int q = 0; q < 2; ++q) {
        const float4 w = ((const float4*)We2)[l5 * 2 + q];
        w2v[q * 4 + 0] = w.x; w2v[q * 4 + 1] = w.y;
        w2v[q * 4 + 2] = w.z; w2v[q * 4 + 3] = w.w;
    }

    float zloc = 0.0f;
    #pragma unroll
    for (int it = 0; it < 8; ++it) {
        const int e = (wid << 1) + sub + (it << 14);    // covers [0, 131072)
        const int src = idx[2 * e];
        const int dst = idx[2 * e + 1];
        const uint4 av = *(const uint4*)(AB + ((size_t)src << 9) + (l5 << 3));
        const uint4 bv = *(const uint4*)(AB + ((size_t)dst << 9) + 256 + (l5 << 3));
        const u32 aw[4] = {av.x, av.y, av.z, av.w};
        const u32 bw[4] = {bv.x, bv.y, bv.z, bv.w};
        float p = 0.0f;
        #pragma unroll
        for (int q = 0; q < 4; ++q) {
            p += fmaxf(bflo(aw[q]) + bflo(bw[q]), 0.0f) * w2v[2 * q];
            p += fmaxf(bfhi(aw[q]) + bfhi(bw[q]), 0.0f) * w2v[2 * q + 1];
        }
        #pragma unroll
        for (int m = 16; m > 0; m >>= 1)
            p += __shfl_xor(p, m, 64);   // xor<32: stays within the half-wave
        const float v = expf(p + be2);
        if (l5 == 0) {
            vbuf[e] = v;
            zloc += v;                   // one lane per edge contributes
        }
    }
    sm[tid] = zloc;
    __syncthreads();
    for (int st = 128; st > 0; st >>= 1) {
        if (tid < st) sm[tid] += sm[tid + st];
        __syncthreads();
    }
    if (tid == 0) part[cb] = sm[0];
}

// fused: finalize Z over part[2048] (redundant per block) + scatter probs
__global__ __launch_bounds__(256)
void scatter_probs(const float* __restrict__ vbuf, const int* __restrict__ idx,
                   const float* __restrict__ part, float* __restrict__ out, int n)
{
    __shared__ float sm[256];
    float a = part[threadIdx.x];
    #pragma unroll
    for (int k = 1; k < 8; ++k)
        a += part[threadIdx.x + k * 256];
    sm[threadIdx.x] = a;
    __syncthreads();
    for (int st = 128; st > 0; st >>= 1) {
        if (threadIdx.x < st) sm[threadIdx.x] += sm[threadIdx.x + st];
        __syncthreads();
    }
    const float Z = sm[0];
    const int e = blockIdx.x * 256 + threadIdx.x;
    if (e < n)
        out[(size_t)idx[2 * e] * N_NODES + idx[2 * e + 1]] = vbuf[e] / Z;
}

// ---------------------------------------------------------------------------
extern "C" void kernel_launch(void* const* d_in, const int* in_sizes, int n_in,
                              void* d_out, int out_size, void* d_ws, size_t ws_size,
                              hipStream_t stream)
{
    const float* ideal = (const float*)d_in[0];   // 4096 x 1024
    const int*   idx   = (const int*)d_in[1];     // E x 2
    const float* W1    = (const float*)d_in[2];   // 256 x 1024
    const float* b1    = (const float*)d_in[3];   // 256
    const float* W2    = (const float*)d_in[4];   // 256 x 256
    const float* b2    = (const float*)d_in[5];   // 256
    const float* We1   = (const float*)d_in[6];   // 256 x 512
    const float* be1   = (const float*)d_in[7];   // 256
    const float* We2   = (const float*)d_in[8];   // 256
    const float* be2   = (const float*)d_in[9];   // 1
    float* out = (float*)d_out;

    char* Wb = (char*)d_ws;
    u16*   wabh = (u16*)(Wb);                          // 256 KB packed Wab
    u16*   h1h  = (u16*)(Wb + (1u << 20));             // 2 MB packed h1
    float* bab  = (float*)(Wb + (3u << 20));           // 2 KB
    u16*   ABbf = (u16*)(Wb + (4u << 20));             // 4 MB bf16 AB row-major
    float* vbuf = (float*)(Wb + (8u << 20));           // 512 KB exp(scores)
    float* part = vbuf + E_EDGES;                      // 2048 partial Z

    // Wab fold + bab (tiny)
    prep_small<<<66, 256, 0, stream>>>(We1, W2, b2, be1, wabh, bab);

    // h1 packed = relu(x @ W1.T + b1); f32->bf16 conversion fused into staging
    mfma_gemm1<<<dim3(128, 4), 256, 0, stream>>>(ideal, W1, b1, h1h);
    // AB bf16 = h1 @ Wab.T + bab        (N = 512: [A | B])
    mfma_gemm2<<<dim3(64, 8), 256, 0, stream>>>(h1h, wabh, bab, ABbf);

    // fill (512 blocks) + exp(scores) + partial Z (2048 blocks), no sync
    edge_fill<<<2560, 256, 0, stream>>>(ABbf, idx, We2, be2, vbuf, part, (float4*)out);
    // Z finalize (redundant per block) + scatter
    scatter_probs<<<512, 256, 0, stream>>>(vbuf, idx, part, out, E_EDGES);
}

// Round 13
// 78.793 us; speedup vs baseline: 1.0756x; 1.0756x over previous
//
#include <hip/hip_runtime.h>
#include <hip/hip_bf16.h>

// TwinPolicy, pure-bf16 MFMA pipeline (5 launches):
//   prep_all: pack x -> xh, pack W1 -> w1h (LDS-transposed, coalesced both
//             directions), fold Wab=(We1@W2) -> wabh, bab
//   gemm1: h1p = pack(relu(x @ W1.T + b1))   BM=32 BN=64, 512 blocks,
//          zero-VALU staging via global_load_lds (R12 lesson: reg-staged
//          f32->bf16 in-flight conversion cost +10us; convert once via HBM)
//   gemm2: ABbf = bf16(h1 @ Wab.T + bab)     64x64, 512 blocks
//   edge_fill (block-specialized): blocks 0..511 zero-fill 67MB output with
//     NONTEMPORAL stores (don't evict the 4MB AB gather set from L2);
//     blocks 512..2559 compute v[e]=exp(s[e]) + block partial Z (no max-sub:
//     |s| = O(1) for these weight scales).
//   scatter_probs: redundant Z-reduce per block + out[src,dst] = v/Z

typedef unsigned short u16;
typedef unsigned int   u32;
typedef __attribute__((ext_vector_type(8))) short bf16x8;
typedef __attribute__((ext_vector_type(4))) float f32x4;

#define N_NODES 4096
#define E_EDGES 131072
#define AS1 __attribute__((address_space(1)))
#define AS3 __attribute__((address_space(3)))

__device__ __forceinline__ u16 f2bf(float f) {
    u32 u = __float_as_uint(f);
    return (u16)((u + 0x7FFFu + ((u >> 16) & 1u)) >> 16);
}
__device__ __forceinline__ float bflo(u32 w) { return __uint_as_float(w << 16); }
__device__ __forceinline__ float bfhi(u32 w) { return __uint_as_float(w & 0xffff0000u); }

// ---------------------------------------------------------------------------
// prep_all (1154 blocks):
//   [0,1024):    pack ideal 64x64 tiles -> xh   (p = b>>4, kc = b&15)
//   [1024,1088): pack W1 tiles -> w1h
//   [1088,1152): Wab[r][c] = (r<256 ? We1a@W2 : We1b@W2), packed bf16 W-layout
//   [1152,1154): bab[r] = (r<256 ? be1[r] : 0) + dot(We1 row-part, b2)
// Pack: read 64B/lane coalesced -> cvt -> LDS (packed order) -> write
// coalesced.  Output bit-identical to the old strided pack_body.
// ---------------------------------------------------------------------------
__global__ __launch_bounds__(256)
void prep_all(const float* __restrict__ ideal, const float* __restrict__ W1,
              const float* __restrict__ We1, const float* __restrict__ W2,
              const float* __restrict__ b2, const float* __restrict__ be1,
              u16* __restrict__ xh, u16* __restrict__ w1h,
              float* __restrict__ bab)
{
    __shared__ u16 tb[4096];        // one 64x64 bf16 tile, packed order
    const int bid = blockIdx.x;
    const int tid = threadIdx.x;

    if (bid < 1088) {
        const float* src_m;
        u16* dst_m;
        int p, kc;
        if (bid < 1024) { src_m = ideal; dst_m = xh;  p = bid >> 4;          kc = bid & 15; }
        else            { src_m = W1;    dst_m = w1h; p = (bid - 1024) >> 4; kc = bid & 15; }

        const int r  = tid >> 2;    // 0..63
        const int cq = tid & 3;     // 0..3 -> 16 consecutive floats
        const float* src = src_m + ((size_t)(p * 64 + r)) * 1024 + kc * 64 + cq * 16;
        const float4 v0 = *(const float4*)src;
        const float4 v1 = *(const float4*)(src + 4);
        const float4 v2 = *(const float4*)(src + 8);
        const float4 v3 = *(const float4*)(src + 12);
        const float vv[16] = {v0.x, v0.y, v0.z, v0.w, v1.x, v1.y, v1.z, v1.w,
                              v2.x, v2.y, v2.z, v2.w, v3.x, v3.y, v3.z, v3.w};
        u32 w[8];
        #pragma unroll
        for (int q = 0; q < 8; ++q)
            w[q] = (u32)f2bf(vv[2 * q]) | ((u32)f2bf(vv[2 * q + 1]) << 16);
        uint4 lo = {w[0], w[1], w[2], w[3]};
        uint4 hi = {w[4], w[5], w[6], w[7]};
        // packed order within tile: [kb(8)][r(64)][e(8)], kb = 2cq (+1)
        *(uint4*)&tb[(((cq << 1) + 0) * 64 + r) << 3] = lo;
        *(uint4*)&tb[(((cq << 1) + 1) * 64 + r) << 3] = hi;
        __syncthreads();
        u16* gdst = dst_m == xh ? xh : w1h;
        gdst += (size_t)(p * 16 + kc) * 4096;
        *(uint4*)(gdst + (tid << 3))         = *(const uint4*)&tb[tid << 3];
        *(uint4*)(gdst + ((tid + 256) << 3)) = *(const uint4*)&tb[(tid + 256) << 3];
    } else if (bid < 1152) {
        // fold Wab (packed bf16 W-operand layout, K=256, KC=4) -> stored in w1h? no: wabh
        // (wabh passed via xh pointer arithmetic below -- see launch: separate arg)
        // NOTE: wabh is passed as `bab - ...`? Kept simple: wabh = (u16*)bab? NO.
        // This branch writes through `xh` region? -- resolved by dedicated pointer:
        // we smuggle wabh as w1h + 524288 (w1h is 512KB = 262144 u16; wabh follows).
        u16* wabh = w1h + 262144;
        const int r0 = (bid - 1088) * 8;
        const int c  = tid;
        float acc[8] = {};
        for (int k = 0; k < 256; ++k) {
            const float w2 = W2[k * 256 + c];
            #pragma unroll
            for (int j = 0; j < 8; ++j) {
                const int r = r0 + j;
                acc[j] += We1[(size_t)(r & 255) * 512 + ((r >> 8) << 8) + k] * w2;
            }
        }
        const int kc = c >> 6, kb = (c >> 3) & 7, e = c & 7;
        #pragma unroll
        for (int j = 0; j < 8; ++j) {
            const int r = r0 + j;
            wabh[(((((size_t)(r >> 6) << 2) + kc) << 3) + kb) * 512 + (size_t)(r & 63) * 8 + e]
                = f2bf(acc[j]);
        }
    } else {
        const int r = (bid - 1152) * 256 + tid;
        const int i = r & 255;
        const int koff = (r >> 8) << 8;
        float acc = (r < 256) ? be1[i] : 0.0f;
        for (int k = 0; k < 256; k += 4) {
            const float4 w = *(const float4*)(We1 + (size_t)i * 512 + koff + k);
            const float4 b = *(const float4*)(b2 + k);
            acc += w.x * b.x + w.y * b.y + w.z * b.z + w.w * b.w;
        }
        bab[r] = acc;
    }
}

// ---------------------------------------------------------------------------
// GEMM1: h1p = relu(x @ W1.T + b1), packed epilogue for gemm2 (KCnext=4).
// BM=32, BN=64, KC=16, 4 waves, grid (128,4) = 512 blocks -> 2 blocks/CU.
// ---------------------------------------------------------------------------
__global__ __launch_bounds__(256)
void mfma_gemm1(const u16* __restrict__ A, const u16* __restrict__ W,
                const float* __restrict__ bias, u16* __restrict__ Cout)
{
    __shared__ u16 As[2][2048];
    __shared__ u16 Bs[2][4096];
    const int tid  = threadIdx.x;
    const int wv   = tid >> 6;
    const int lane = tid & 63;
    const int bp   = blockIdx.x;          // 0..127: 32-row block
    const int bn   = blockIdx.y;          // 0..3:   64-col panel
    const int p    = bp >> 1;
    const int r0   = (bp & 1) << 5;
    const int KC   = 16;

    auto stage = [&](int b, int t) {
        {
            const int kb = tid >> 5, r = tid & 31;
            const u16* ga = A + (((((size_t)p * KC + t) << 3) + kb) << 9) + (size_t)(r0 + r) * 8;
            __builtin_amdgcn_global_load_lds((const AS1 u32*)ga,
                (AS3 u32*)(&As[b][tid << 3]), 16, 0, 0);
        }
        const u16* gw = W + (((size_t)bn * KC + t) << 12);
        #pragma unroll
        for (int c = 0; c < 2; ++c) {
            const int ch = (wv << 1) + c;
            __builtin_amdgcn_global_load_lds(
                (const AS1 u32*)(gw + (ch << 9) + (lane << 3)),
                (AS3 u32*)(&Bs[b][ch << 9]), 16, 0, 0);
        }
    };

    f32x4 acc[2];
    #pragma unroll
    for (int m = 0; m < 2; ++m) acc[m] = (f32x4){0.f, 0.f, 0.f, 0.f};

    const int kq  = lane >> 4;
    const int r16 = lane & 15;

    auto compute = [&](int b) {
        #pragma unroll
        for (int s = 0; s < 2; ++s) {
            const int kb = (s << 2) + kq;
            const bf16x8 bf = *(const bf16x8*)&Bs[b][((kb << 6) + (wv << 4) + r16) << 3];
            #pragma unroll
            for (int m = 0; m < 2; ++m) {
                const bf16x8 af = *(const bf16x8*)&As[b][((kb << 5) + (m << 4) + r16) << 3];
                acc[m] = __builtin_amdgcn_mfma_f32_16x16x32_bf16(af, bf, acc[m], 0, 0, 0);
            }
        }
    };

    stage(0, 0);
    __syncthreads();
    int buf = 0;
    for (int t = 0; t < KC; ++t) {
        if (t + 1 < KC) stage(buf ^ 1, t + 1);
        compute(buf);
        __syncthreads();
        buf ^= 1;
    }

    // C/D: col=lane&15, row=(lane>>4)*4+j.  Packed A-layout epilogue (KCnext=4).
    const int col  = (bn << 6) + (wv << 4) + r16;
    const float bv = bias[col];
    const int kb2  = (wv << 1) | (r16 >> 3);
    const int e2   = r16 & 7;
    u16* Cp = Cout + (((((size_t)p * 4 + bn) << 3) + kb2) << 9) + e2;
    #pragma unroll
    for (int m = 0; m < 2; ++m)
        #pragma unroll
        for (int j = 0; j < 4; ++j) {
            const float v = fmaxf(acc[m][j] + bv, 0.0f);
            const int r64 = r0 + (kq << 2) + (m << 4) + j;
            Cp[(size_t)r64 << 3] = f2bf(v);
        }
}

// ---------------------------------------------------------------------------
// GEMM2: AB = h1 @ Wab.T + bab, bf16 row-major out.
// 64x64 tile, KC=4, 4 waves, grid (64,8) = 512 blocks.
// ---------------------------------------------------------------------------
__global__ __launch_bounds__(256)
void mfma_gemm2(const u16* __restrict__ A, const u16* __restrict__ W,
                const float* __restrict__ bias, u16* __restrict__ Cout)
{
    __shared__ u16 As[2][4096];
    __shared__ u16 Bs[2][4096];
    const int tid  = threadIdx.x;
    const int wv   = tid >> 6;
    const int lane = tid & 63;
    const int bp   = blockIdx.x;
    const int bn   = blockIdx.y;
    const int KC   = 4;
    const int Nout = 512;

    auto stage = [&](int b, int t) {
        const u16* ga = A + (((size_t)bp * KC + t) << 12);
        const u16* gw = W + (((size_t)bn * KC + t) << 12);
        #pragma unroll
        for (int c = 0; c < 2; ++c) {
            const int ch = (wv << 1) + c;
            __builtin_amdgcn_global_load_lds(
                (const AS1 u32*)(ga + (ch << 9) + (lane << 3)),
                (AS3 u32*)(&As[b][ch << 9]), 16, 0, 0);
            __builtin_amdgcn_global_load_lds(
                (const AS1 u32*)(gw + (ch << 9) + (lane << 3)),
                (AS3 u32*)(&Bs[b][ch << 9]), 16, 0, 0);
        }
    };

    f32x4 acc[4];
    #pragma unroll
    for (int m = 0; m < 4; ++m) acc[m] = (f32x4){0.f, 0.f, 0.f, 0.f};

    const int kq  = lane >> 4;
    const int r16 = lane & 15;

    auto compute = [&](int b) {
        #pragma unroll
        for (int s = 0; s < 2; ++s) {
            const int kb = (s << 2) + kq;
            const bf16x8 bf = *(const bf16x8*)&Bs[b][((kb << 6) + (wv << 4) + r16) << 3];
            #pragma unroll
            for (int m = 0; m < 4; ++m) {
                const bf16x8 af = *(const bf16x8*)&As[b][((kb << 6) + (m << 4) + r16) << 3];
                acc[m] = __builtin_amdgcn_mfma_f32_16x16x32_bf16(af, bf, acc[m], 0, 0, 0);
            }
        }
    };

    stage(0, 0);
    __syncthreads();
    int buf = 0;
    for (int t = 0; t < KC; ++t) {
        if (t + 1 < KC) stage(buf ^ 1, t + 1);
        compute(buf);
        __syncthreads();
        buf ^= 1;
    }

    const int col  = (bn << 6) + (wv << 4) + r16;
    const float bv = bias[col];
    #pragma unroll
    for (int m = 0; m < 4; ++m)
        #pragma unroll
        for (int j = 0; j < 4; ++j) {
            const float v = acc[m][j] + bv;
            const int row = (bp << 6) + (kq << 2) + (m << 4) + j;
            Cout[(size_t)row * Nout + col] = f2bf(v);
        }
}

// ---------------------------------------------------------------------------
// Block-specialized edge + fill (NO inter-block sync needed):
//   blocks [0,512):    zero-fill 67MB output, NONTEMPORAL (keep AB L2-hot)
//   blocks [512,2560): v[e] = exp(score[e]) (no max-sub; |s| = O(1)),
//                      block-partial Z -> part[cb] (only l5==0 lanes add).
// ---------------------------------------------------------------------------
__global__ __launch_bounds__(256)
void edge_fill(const u16* __restrict__ AB, const int* __restrict__ idx,
               const float* __restrict__ We2, const float* __restrict__ be2p,
               float* __restrict__ vbuf, float* __restrict__ part,
               f32x4* __restrict__ out4)
{
    const int bid = blockIdx.x;
    const int tid = threadIdx.x;

    if (bid < 512) {
        // 512 blk * 256 thr * 32 f32x4 * 16B = 67.1 MB
        f32x4* op = out4 + (size_t)bid * 8192 + tid;
        const f32x4 z = {0.f, 0.f, 0.f, 0.f};
        #pragma unroll 8
        for (int q = 0; q < 32; ++q)
            __builtin_nontemporal_store(z, op + (size_t)q * 256);
        return;
    }

    __shared__ float sm[256];
    const int cb   = bid - 512;                  // 0..2047
    const int lane = tid & 63;
    const int sub  = lane >> 5;
    const int l5   = lane & 31;
    const int wid  = (cb * 256 + tid) >> 6;      // 0..8191
    const float be2 = be2p[0];

    float w2v[8];
    #pragma unroll
    for (int q = 0; q < 2; ++q) {
        const float4 w = ((const float4*)We2)[l5 * 2 + q];
        w2v[q * 4 + 0] = w.x; w2v[q * 4 + 1] = w.y;
        w2v[q * 4 + 2] = w.z; w2v[q * 4 + 3] = w.w;
    }

    float zloc = 0.0f;
    #pragma unroll
    for (int it = 0; it < 8; ++it) {
        const int e = (wid << 1) + sub + (it << 14);    // covers [0, 131072)
        const int src = idx[2 * e];
        const int dst = idx[2 * e + 1];
        const uint4 av = *(const uint4*)(AB + ((size_t)src << 9) + (l5 << 3));
        const uint4 bv = *(const uint4*)(AB + ((size_t)dst << 9) + 256 + (l5 << 3));
        const u32 aw[4] = {av.x, av.y, av.z, av.w};
        const u32 bw[4] = {bv.x, bv.y, bv.z, bv.w};
        float p = 0.0f;
        #pragma unroll
        for (int q = 0; q < 4; ++q) {
            p += fmaxf(bflo(aw[q]) + bflo(bw[q]), 0.0f) * w2v[2 * q];
            p += fmaxf(bfhi(aw[q]) + bfhi(bw[q]), 0.0f) * w2v[2 * q + 1];
        }
        #pragma unroll
        for (int m = 16; m > 0; m >>= 1)
            p += __shfl_xor(p, m, 64);   // xor<32: stays within the half-wave
        const float v = expf(p + be2);
        if (l5 == 0) {
            vbuf[e] = v;
            zloc += v;                   // one lane per edge contributes
        }
    }
    sm[tid] = zloc;
    __syncthreads();
    for (int st = 128; st > 0; st >>= 1) {
        if (tid < st) sm[tid] += sm[tid + st];
        __syncthreads();
    }
    if (tid == 0) part[cb] = sm[0];
}

// fused: finalize Z over part[2048] (redundant per block) + scatter probs
__global__ __launch_bounds__(256)
void scatter_probs(const float* __restrict__ vbuf, const int* __restrict__ idx,
                   const float* __restrict__ part, float* __restrict__ out, int n)
{
    __shared__ float sm[256];
    float a = part[threadIdx.x];
    #pragma unroll
    for (int k = 1; k < 8; ++k)
        a += part[threadIdx.x + k * 256];
    sm[threadIdx.x] = a;
    __syncthreads();
    for (int st = 128; st > 0; st >>= 1) {
        if (threadIdx.x < st) sm[threadIdx.x] += sm[threadIdx.x + st];
        __syncthreads();
    }
    const float Z = sm[0];
    const int e = blockIdx.x * 256 + threadIdx.x;
    if (e < n)
        out[(size_t)idx[2 * e] * N_NODES + idx[2 * e + 1]] = vbuf[e] / Z;
}

// ---------------------------------------------------------------------------
extern "C" void kernel_launch(void* const* d_in, const int* in_sizes, int n_in,
                              void* d_out, int out_size, void* d_ws, size_t ws_size,
                              hipStream_t stream)
{
    const float* ideal = (const float*)d_in[0];   // 4096 x 1024
    const int*   idx   = (const int*)d_in[1];     // E x 2
    const float* W1    = (const float*)d_in[2];   // 256 x 1024
    const float* b1    = (const float*)d_in[3];   // 256
    const float* W2    = (const float*)d_in[4];   // 256 x 256
    const float* b2    = (const float*)d_in[5];   // 256
    const float* We1   = (const float*)d_in[6];   // 256 x 512
    const float* be1   = (const float*)d_in[7];   // 256
    const float* We2   = (const float*)d_in[8];   // 256
    const float* be2   = (const float*)d_in[9];   // 1
    float* out = (float*)d_out;

    char* Wb = (char*)d_ws;
    u16*   xh   = (u16*)(Wb);                          // 8 MB packed x
    u16*   w1h  = (u16*)(Wb + (8u << 20));             // 512 KB packed W1
    u16*   wabh = w1h + 262144;                        // 256 KB packed Wab (follows w1h)
    u16*   h1h  = (u16*)(Wb + (9u << 20));             // 2 MB packed h1
    float* bab  = (float*)(Wb + (11u << 20));          // 2 KB
    u16*   ABbf = (u16*)(Wb + (12u << 20));            // 4 MB bf16 AB row-major
    float* vbuf = (float*)(Wb + (16u << 20));          // 512 KB exp(scores)
    float* part = vbuf + E_EDGES;                      // 2048 partial Z

    // pack x, pack W1 (LDS-transposed), fold Wab, bab
    prep_all<<<1154, 256, 0, stream>>>(ideal, W1, We1, W2, b2, be1, xh, w1h, bab);

    // h1 packed = relu(x @ W1.T + b1)
    mfma_gemm1<<<dim3(128, 4), 256, 0, stream>>>(xh, w1h, b1, h1h);
    // AB bf16 = h1 @ Wab.T + bab        (N = 512: [A | B])
    mfma_gemm2<<<dim3(64, 8), 256, 0, stream>>>(h1h, wabh, bab, ABbf);

    // fill (512 blocks, nontemporal) + exp(scores) + partial Z (2048 blocks)
    edge_fill<<<2560, 256, 0, stream>>>(ABbf, idx, We2, be2, vbuf, part, (f32x4*)out);
    // Z finalize (redundant per block) + scatter
    scatter_probs<<<512, 256, 0, stream>>>(vbuf, idx, part, out, E_EDGES);
}

// Round 14
// 76.992 us; speedup vs baseline: 1.1007x; 1.0234x over previous
//
#include <hip/hip_runtime.h>
#include <hip/hip_bf16.h>

// TwinPolicy, pure-bf16 MFMA pipeline (4 launches):
//   prep_weights: pack W1 -> w1h (strided pack; L3 absorbs the strided reads),
//                 fold Wab=(We1@W2) -> wabh, bab
//   gemm_fused: per 16-row block: h1 = relu(x @ W1.T + b1) kept in LDS,
//               then AB = h1 @ Wab.T + bab written directly (bit-identical
//               k-order to the old gemm1+gemm2 pair; x converted f32->bf16
//               in-staging, read exactly once)
//   edge_fill (block-specialized): blocks 0..511 zero-fill 67MB output;
//     blocks 512..2559 compute v[e]=exp(s[e]) + block partial Z (no max-sub:
//     |s| = O(1) for these weight scales)
//   scatter_probs: redundant Z-reduce per block + out[src,dst] = v/Z

typedef unsigned short u16;
typedef unsigned int   u32;
typedef __attribute__((ext_vector_type(8))) short bf16x8;
typedef __attribute__((ext_vector_type(4))) float f32x4;

#define N_NODES 4096
#define E_EDGES 131072
#define AS1 __attribute__((address_space(1)))
#define AS3 __attribute__((address_space(3)))

__device__ __forceinline__ u16 f2bf(float f) {
    u32 u = __float_as_uint(f);
    return (u16)((u + 0x7FFFu + ((u >> 16) & 1u)) >> 16);
}
__device__ __forceinline__ float bflo(u32 w) { return __uint_as_float(w << 16); }
__device__ __forceinline__ float bfhi(u32 w) { return __uint_as_float(w & 0xffff0000u); }

// ---------------------------------------------------------------------------
// Pack f32 [M][K] -> bf16, MFMA-ready layout (strided reads; inputs are
// L3-resident so the strided pattern costs no HBM -- R13 lesson):
// elem(row,k) -> ((((row>>6)*KC + (k>>6))*8 + ((k>>3)&7))*64 + (row&63))*8 + (k&7)
// ---------------------------------------------------------------------------
__device__ __forceinline__ void pack_body(const float* __restrict__ in,
                                          u16* __restrict__ hi, int K, int kcs, int gid)
{
    const int r   = gid & 63;
    const int kb  = (gid >> 6) & 7;
    const int pkc = gid >> 9;
    const int kc  = pkc & ((1 << kcs) - 1);
    const int p   = pkc >> kcs;
    const size_t row = ((size_t)p << 6) | r;
    const int k0 = (kc << 6) | (kb << 3);

    const float* src = in + row * (size_t)K + k0;
    const float4 v0 = *(const float4*)src;
    const float4 v1 = *(const float4*)(src + 4);
    const float vv[8] = {v0.x, v0.y, v0.z, v0.w, v1.x, v1.y, v1.z, v1.w};

    u32 hw[4];
    #pragma unroll
    for (int q = 0; q < 4; ++q)
        hw[q] = (u32)f2bf(vv[2 * q]) | ((u32)f2bf(vv[2 * q + 1]) << 16);
    uint4 hv = {hw[0], hw[1], hw[2], hw[3]};
    *(uint4*)(hi + (size_t)gid * 8) = hv;
}

// ---------------------------------------------------------------------------
// prep_weights (194 blocks):
//   [0,128):   pack W1 (256x1024) -> w1h
//   [128,192): Wab[r][c] = (r<256 ? We1a@W2 : We1b@W2), packed bf16 W-layout
//   [192,194): bab[r] = (r<256 ? be1[r] : 0) + dot(We1 row-part, b2)
// ---------------------------------------------------------------------------
__global__ __launch_bounds__(256)
void prep_weights(const float* __restrict__ W1, const float* __restrict__ We1,
                  const float* __restrict__ W2, const float* __restrict__ b2,
                  const float* __restrict__ be1,
                  u16* __restrict__ w1h, u16* __restrict__ wabh,
                  float* __restrict__ bab)
{
    const int bid = blockIdx.x;
    if (bid < 128) {
        pack_body(W1, w1h, 1024, 4, bid * 256 + threadIdx.x);
    } else if (bid < 192) {
        const int r0 = (bid - 128) * 8;
        const int c  = threadIdx.x;
        float acc[8] = {};
        for (int k = 0; k < 256; ++k) {
            const float w2 = W2[k * 256 + c];
            #pragma unroll
            for (int j = 0; j < 8; ++j) {
                const int r = r0 + j;
                acc[j] += We1[(size_t)(r & 255) * 512 + ((r >> 8) << 8) + k] * w2;
            }
        }
        const int kc = c >> 6, kb = (c >> 3) & 7, e = c & 7;
        #pragma unroll
        for (int j = 0; j < 8; ++j) {
            const int r = r0 + j;
            wabh[(((((size_t)(r >> 6) << 2) + kc) << 3) + kb) * 512 + (size_t)(r & 63) * 8 + e]
                = f2bf(acc[j]);
        }
    } else {
        const int r = (bid - 192) * 256 + threadIdx.x;
        const int i = r & 255;
        const int koff = (r >> 8) << 8;
        float acc = (r < 256) ? be1[i] : 0.0f;
        for (int k = 0; k < 256; k += 4) {
            const float4 w = *(const float4*)(We1 + (size_t)i * 512 + koff + k);
            const float4 b = *(const float4*)(b2 + k);
            acc += w.x * b.x + w.y * b.y + w.z * b.z + w.w * b.w;
        }
        bab[r] = acc;
    }
}

// ---------------------------------------------------------------------------
// gemm_fused: 256 blocks x 256 thr, block b owns rows [16b, 16b+16).
// Layer 1: h1 = relu(x @ W1.T + b1), M=16, N=256 (wave wv = cols 64wv..),
//   K=1024 over 16 steps. A staged from f32 x with in-staging cvt (32B load,
//   4 cvt, one 16B ds_write per thread/step). W1 via global_load_lds (packed).
//   h1 parked in LDS in layer-2 A-fragment layout [kb32][row16][e8].
// Layer 2: AB[16 x 512] = h1 @ Wab.T + bab; B-frags read from global (L2-hot).
// k-order t-asc, s-asc everywhere == old gemm1/gemm2 -> bit-identical.
// ---------------------------------------------------------------------------
__global__ __launch_bounds__(256, 2)
void gemm_fused(const float* __restrict__ X, const u16* __restrict__ W1p,
                const u16* __restrict__ Wabp, const float* __restrict__ b1,
                const float* __restrict__ bab, u16* __restrict__ ABout)
{
    __shared__ u16 As[2][1024];      // [kb8][r16][e8]  (2 KB each)
    __shared__ u16 Bs[2][16384];     // [pan4][kb8][c64][e8] (32 KB each)
    __shared__ u16 H1[4096];         // [kb32][r16][e8] (8 KB)
    const int tid  = threadIdx.x;
    const int wv   = tid >> 6;
    const int lane = tid & 63;
    const int kq   = lane >> 4;
    const int r16  = lane & 15;
    const int rowbase = blockIdx.x << 4;

    // A staging: threads 0..127, thread = (row = tid&15, kb = tid>>4)
    const int arow = tid & 15;
    const int akb  = tid >> 4;
    const float* gx = X + (size_t)(rowbase + arow) * 1024 + (akb << 3);

    float4 ra0, ra1;
    auto regloadA = [&](int t) {
        if (tid < 128) {
            const float* p = gx + t * 64;
            ra0 = *(const float4*)p;
            ra1 = *(const float4*)(p + 4);
        }
    };
    auto storeA = [&](int b) {
        if (tid < 128) {
            const float av[8] = {ra0.x, ra0.y, ra0.z, ra0.w,
                                 ra1.x, ra1.y, ra1.z, ra1.w};
            u32 w[4];
            #pragma unroll
            for (int q = 0; q < 4; ++q)
                w[q] = (u32)f2bf(av[2 * q]) | ((u32)f2bf(av[2 * q + 1]) << 16);
            uint4 v = {w[0], w[1], w[2], w[3]};
            *(uint4*)&As[b][((akb << 4) + arow) << 3] = v;
        }
    };
    auto stageW = [&](int b, int t) {
        #pragma unroll
        for (int pan = 0; pan < 4; ++pan) {
            const u16* gw = W1p + (((size_t)pan * 16 + t) << 12);
            #pragma unroll
            for (int c = 0; c < 2; ++c) {
                const int ch = (wv << 1) + c;
                __builtin_amdgcn_global_load_lds(
                    (const AS1 u32*)(gw + (ch << 9) + (lane << 3)),
                    (AS3 u32*)(&Bs[b][(pan << 12) + (ch << 9) + (lane << 3)]),
                    16, 0, 0);
            }
        }
    };

    f32x4 acc[4];
    #pragma unroll
    for (int n = 0; n < 4; ++n) acc[n] = (f32x4){0.f, 0.f, 0.f, 0.f};

    auto compute1 = [&](int b) {
        #pragma unroll
        for (int s = 0; s < 2; ++s) {
            const int kb = (s << 2) + kq;
            const bf16x8 af = *(const bf16x8*)&As[b][((kb << 4) + r16) << 3];
            #pragma unroll
            for (int n = 0; n < 4; ++n) {
                const bf16x8 bf = *(const bf16x8*)
                    &Bs[b][(wv << 12) + (((kb << 6) + (n << 4) + r16) << 3)];
                acc[n] = __builtin_amdgcn_mfma_f32_16x16x32_bf16(af, bf, acc[n], 0, 0, 0);
            }
        }
    };

    stageW(0, 0);
    regloadA(0);
    storeA(0);
    __syncthreads();
    int buf = 0;
    for (int t = 0; t < 16; ++t) {
        if (t + 1 < 16) { stageW(buf ^ 1, t + 1); regloadA(t + 1); }
        compute1(buf);
        if (t + 1 < 16) storeA(buf ^ 1);
        __syncthreads();
        buf ^= 1;
    }

    // layer-1 epilogue -> H1 in layer-2 A-frag layout.
    // D-frag: col=r16 (h1 col c), row=kq*4+j.  c = wv*64+n*16+r16.
    #pragma unroll
    for (int n = 0; n < 4; ++n) {
        const int c  = (wv << 6) + (n << 4) + r16;
        const float bv = b1[c];
        const int kb2 = (wv << 3) + (n << 1) + (r16 >> 3);
        #pragma unroll
        for (int j = 0; j < 4; ++j) {
            const float v = fmaxf(acc[n][j] + bv, 0.0f);
            H1[(((kb2 << 4) + (kq << 2) + j) << 3) + (r16 & 7)] = f2bf(v);
        }
    }
    __syncthreads();

    // layer 2: wave wv owns cols [wv*128, wv*128+128)
    f32x4 acc2[2][4];
    #pragma unroll
    for (int p2 = 0; p2 < 2; ++p2)
        #pragma unroll
        for (int n = 0; n < 4; ++n) acc2[p2][n] = (f32x4){0.f, 0.f, 0.f, 0.f};

    for (int t = 0; t < 4; ++t) {
        #pragma unroll
        for (int s = 0; s < 2; ++s) {
            const int kb32 = ((((t << 1) + s) << 2) + kq);
            const bf16x8 af = *(const bf16x8*)&H1[((kb32 << 4) + r16) << 3];
            #pragma unroll
            for (int p2 = 0; p2 < 2; ++p2) {
                const int bn = (wv << 1) + p2;
                const u16* wb = Wabp + ((((size_t)bn << 2) + t) * 8 + (s << 2) + kq) * 512;
                #pragma unroll
                for (int n = 0; n < 4; ++n) {
                    const bf16x8 bf = *(const bf16x8*)(wb + (((n << 4) + r16) << 3));
                    acc2[p2][n] = __builtin_amdgcn_mfma_f32_16x16x32_bf16(af, bf, acc2[p2][n], 0, 0, 0);
                }
            }
        }
    }

    #pragma unroll
    for (int p2 = 0; p2 < 2; ++p2)
        #pragma unroll
        for (int n = 0; n < 4; ++n) {
            const int col = (wv << 7) + (p2 << 6) + (n << 4) + r16;
            const float bv = bab[col];
            #pragma unroll
            for (int j = 0; j < 4; ++j) {
                const int row = rowbase + (kq << 2) + j;
                ABout[(size_t)row * 512 + col] = f2bf(acc2[p2][n][j] + bv);
            }
        }
}

// ---------------------------------------------------------------------------
// Block-specialized edge + fill (NO inter-block sync needed):
//   blocks [0,512):    zero-fill 67MB output (32 float4/thread, plain stores)
//   blocks [512,2560): v[e] = exp(score[e]) (no max-sub; |s| = O(1)),
//                      block-partial Z -> part[cb] (only l5==0 lanes add).
// ---------------------------------------------------------------------------
__global__ __launch_bounds__(256)
void edge_fill(const u16* __restrict__ AB, const int* __restrict__ idx,
               const float* __restrict__ We2, const float* __restrict__ be2p,
               float* __restrict__ vbuf, float* __restrict__ part,
               float4* __restrict__ out4)
{
    const int bid = blockIdx.x;
    const int tid = threadIdx.x;

    if (bid < 512) {
        float4* op = out4 + (size_t)bid * 8192 + tid;
        const float4 z = {0.f, 0.f, 0.f, 0.f};
        #pragma unroll 8
        for (int q = 0; q < 32; ++q)
            op[(size_t)q * 256] = z;
        return;
    }

    __shared__ float sm[256];
    const int cb   = bid - 512;                  // 0..2047
    const int lane = tid & 63;
    const int sub  = lane >> 5;
    const int l5   = lane & 31;
    const int wid  = (cb * 256 + tid) >> 6;      // 0..8191
    const float be2 = be2p[0];

    float w2v[8];
    #pragma unroll
    for (int q = 0; q < 2; ++q) {
        const float4 w = ((const float4*)We2)[l5 * 2 + q];
        w2v[q * 4 + 0] = w.x; w2v[q * 4 + 1] = w.y;
        w2v[q * 4 + 2] = w.z; w2v[q * 4 + 3] = w.w;
    }

    float zloc = 0.0f;
    #pragma unroll
    for (int it = 0; it < 8; ++it) {
        const int e = (wid << 1) + sub + (it << 14);    // covers [0, 131072)
        const int src = idx[2 * e];
        const int dst = idx[2 * e + 1];
        const uint4 av = *(const uint4*)(AB + ((size_t)src << 9) + (l5 << 3));
        const uint4 bv = *(const uint4*)(AB + ((size_t)dst << 9) + 256 + (l5 << 3));
        const u32 aw[4] = {av.x, av.y, av.z, av.w};
        const u32 bw[4] = {bv.x, bv.y, bv.z, bv.w};
        float p = 0.0f;
        #pragma unroll
        for (int q = 0; q < 4; ++q) {
            p += fmaxf(bflo(aw[q]) + bflo(bw[q]), 0.0f) * w2v[2 * q];
            p += fmaxf(bfhi(aw[q]) + bfhi(bw[q]), 0.0f) * w2v[2 * q + 1];
        }
        #pragma unroll
        for (int m = 16; m > 0; m >>= 1)
            p += __shfl_xor(p, m, 64);   // xor<32: stays within the half-wave
        const float v = expf(p + be2);
        if (l5 == 0) {
            vbuf[e] = v;
            zloc += v;                   // one lane per edge contributes
        }
    }
    sm[tid] = zloc;
    __syncthreads();
    for (int st = 128; st > 0; st >>= 1) {
        if (tid < st) sm[tid] += sm[tid + st];
        __syncthreads();
    }
    if (tid == 0) part[cb] = sm[0];
}

// fused: finalize Z over part[2048] (redundant per block) + scatter probs
__global__ __launch_bounds__(256)
void scatter_probs(const float* __restrict__ vbuf, const int* __restrict__ idx,
                   const float* __restrict__ part, float* __restrict__ out, int n)
{
    __shared__ float sm[256];
    float a = part[threadIdx.x];
    #pragma unroll
    for (int k = 1; k < 8; ++k)
        a += part[threadIdx.x + k * 256];
    sm[threadIdx.x] = a;
    __syncthreads();
    for (int st = 128; st > 0; st >>= 1) {
        if (threadIdx.x < st) sm[threadIdx.x] += sm[threadIdx.x + st];
        __syncthreads();
    }
    const float Z = sm[0];
    const int e = blockIdx.x * 256 + threadIdx.x;
    if (e < n)
        out[(size_t)idx[2 * e] * N_NODES + idx[2 * e + 1]] = vbuf[e] / Z;
}

// ---------------------------------------------------------------------------
extern "C" void kernel_launch(void* const* d_in, const int* in_sizes, int n_in,
                              void* d_out, int out_size, void* d_ws, size_t ws_size,
                              hipStream_t stream)
{
    const float* ideal = (const float*)d_in[0];   // 4096 x 1024
    const int*   idx   = (const int*)d_in[1];     // E x 2
    const float* W1    = (const float*)d_in[2];   // 256 x 1024
    const float* b1    = (const float*)d_in[3];   // 256
    const float* W2    = (const float*)d_in[4];   // 256 x 256
    const float* b2    = (const float*)d_in[5];   // 256
    const float* We1   = (const float*)d_in[6];   // 256 x 512
    const float* be1   = (const float*)d_in[7];   // 256
    const float* We2   = (const float*)d_in[8];   // 256
    const float* be2   = (const float*)d_in[9];   // 1
    float* out = (float*)d_out;

    char* Wb = (char*)d_ws;
    u16*   w1h  = (u16*)(Wb);                          // 512 KB packed W1
    u16*   wabh = (u16*)(Wb + (512u << 10));           // 256 KB packed Wab
    float* bab  = (float*)(Wb + (768u << 10));         // 2 KB
    u16*   ABbf = (u16*)(Wb + (1u << 20));             // 4 MB bf16 AB row-major
    float* vbuf = (float*)(Wb + (6u << 20));           // 512 KB exp(scores)
    float* part = vbuf + E_EDGES;                      // 2048 partial Z

    // pack W1, fold Wab, bab
    prep_weights<<<194, 256, 0, stream>>>(W1, We1, W2, b2, be1, w1h, wabh, bab);

    // AB = relu(x @ W1.T + b1) @ Wab.T + bab, fused (x read once, f32)
    gemm_fused<<<256, 256, 0, stream>>>(ideal, w1h, wabh, b1, bab, ABbf);

    // fill (512 blocks) + exp(scores) + partial Z (2048 blocks), no sync
    edge_fill<<<2560, 256, 0, stream>>>(ABbf, idx, We2, be2, vbuf, part, (float4*)out);
    // Z finalize (redundant per block) + scatter
    scatter_probs<<<512, 256, 0, stream>>>(vbuf, idx, part, out, E_EDGES);
}